// Round 13
// baseline (97.810 us; speedup 1.0000x reference)
//
#include <hip/hip_runtime.h>
#include <math.h>

#define N_ 16
#define T_ 8192
#define C_ 128
#define K_ 64

#define TPB_A 128      // t per assign block
#define BPN_A 64       // assign blocks per n
#define TCH 256        // t per vlad block
#define NCH 32         // vlad chunks per n

// ---------------- OLD (fallback) ws layout in floats (34.63 MB) -------------
#define WS_VLAD 0
#define WS_ASUM 131072
#define WS_GSUM 132096
#define WS_ZEND 132608
#define WS_RNORM 132608
#define WS_W2F   263680
#define WS_P1    267776
#define WS_AG    268288
#define WS_PART  4462592       // -> 8656896 floats

// ---------------- NEW ws layout in floats (67.15 MB) ------------------------
#define NW_ASUM 0              // 1024
#define NW_GSUM 1024           // 16
#define NW_MCS  2048           // N*C = 2048 -> 4096  (masked colsum)
#define NW_W2F  4096           // 4096 floats (8192 bf16)
#define NW_P1   8192           // 512 -> 8704
#define NW_XTM  8960           // N*T*C bf16 = 8388608 floats -> 8397568
#define NW_AG   8397568        // N*T*K bf16 = 4194304 floats -> 12591872
#define NW_PART 12591872       // N*NCH*K*C  = 4194304 floats -> 16786176
#define NW_TOTAL 16786176

typedef __attribute__((ext_vector_type(8))) short short8;
typedef __attribute__((ext_vector_type(4))) float f32x4;

__device__ __forceinline__ uint bfr(float f) {          // fp32 -> bf16 (RNE)
    uint u = __float_as_uint(f);
    return (u + 0x7fffu + ((u >> 16) & 1u)) >> 16;
}
__device__ __forceinline__ uint pack2(float lo, float hi) {
    return bfr(lo) | (bfr(hi) << 16);
}
__device__ __forceinline__ float bfu(ushort u) {
    return __uint_as_float(((uint)u) << 16);
}

// Precompute constant tables + zero the accumulator region. grid = 4 blocks.
__global__ void setup_k(const float* __restrict__ conv1_w,
                        const float* __restrict__ bn1_g, const float* __restrict__ bn1_b,
                        const float* __restrict__ bn1_m, const float* __restrict__ bn1_v,
                        const float* __restrict__ conv2_w,
                        const float* __restrict__ bn2_g, const float* __restrict__ bn2_v,
                        ushort* __restrict__ w2t, float* __restrict__ p1,
                        float* __restrict__ zr, int zcnt) {
    const int gt = blockIdx.x * 256 + threadIdx.x;   // 0..1023
    for (int idx = gt; idx < 8192; idx += 1024) {
        int j = idx & 7;
        int lane = (idx >> 3) & 63;
        int mq = idx >> 9;
        int m = mq >> 2, q = mq & 3;
        int fr = lane & 15, fg = lane >> 4;
        int k = m * 16 + fr;
        float sck = bn2_g[k] * rsqrtf(bn2_v[k] + 1e-5f);
        float v = conv2_w[k * C_ + q * 32 + fg * 8 + j] * sck;
        w2t[idx] = (ushort)bfr(v);
    }
    for (int c = gt; c < C_; c += 1024) {
        float s1 = bn1_g[c] * rsqrtf(bn1_v[c] + 1e-5f);
        p1[c]       = conv1_w[c * 9 + 1] * s1;
        p1[128 + c] = conv1_w[c * 9 + 4] * s1;
        p1[256 + c] = conv1_w[c * 9 + 7] * s1;
        p1[384 + c] = bn1_b[c] - bn1_m[c] * s1;
    }
    for (int i = gt; i < zcnt; i += 1024) zr[i] = 0.0f;
}

// ================= NEW PATH =================================================

// Normalize rows, emit xn bf16 t-minor chunks [chunk=32t][128c][32t], and
// accumulate the masked-region (t >= Lc, chunk-aligned) colsum into mcs[n][c].
__global__ __launch_bounds__(256, 8) void xnorm_k(const float* __restrict__ x,
                                                  ushort* __restrict__ xtm,
                                                  const int* __restrict__ length,
                                                  float* __restrict__ mcs) {
    __shared__ uint xt[32][64];            // packed c-pairs, [t][c2]
    const int tid = threadIdx.x;
    const int lane = tid & 63;
    const int w = tid >> 6;
    const int n = blockIdx.x >> 8;
    const int tloc = (blockIdx.x & 255) * 32;
    const size_t row0 = (size_t)blockIdx.x * 32;

#pragma unroll
    for (int i = 0; i < 8; ++i) {
        int r = w * 8 + i;
        const float* xr = x + (row0 + r) * C_;
        float2 v = *(const float2*)&xr[lane * 2];
        float ss = v.x * v.x + v.y * v.y;
#pragma unroll
        for (int m = 1; m < 64; m <<= 1) ss += __shfl_xor(ss, m, 64);
        float rn = 1.0f / fmaxf(sqrtf(ss), 1e-12f);
        xt[r][lane] = pack2(v.x * rn, v.y * rn);
    }
    __syncthreads();

    uint4* dst = (uint4*)(xtm + (size_t)blockIdx.x * 4096);
#pragma unroll
    for (int uu = 0; uu < 2; ++uu) {
        int u = tid * 2 + uu;              // 0..511
        int c = u >> 2, j = u & 3;
        int cw = c >> 1, sh = (c & 1) * 16;
        uint o[4];
#pragma unroll
        for (int q = 0; q < 4; ++q) {
            uint lo = (xt[j * 8 + q * 2][cw] >> sh) & 0xffffu;
            uint hi = (xt[j * 8 + q * 2 + 1][cw] >> sh) & 0xffffu;
            o[q] = lo | (hi << 16);
        }
        uint4 v; v.x = o[0]; v.y = o[1]; v.z = o[2]; v.w = o[3];
        dst[u] = v;
    }

    // masked-region colsum (bf16 values, fp32 sum) — vlad chunks with tb >= L
    // are skipped entirely; their contribution is (1/64) * this colsum.
    const int L = length[n];
    const int Lc = ((L + 255) >> 8) << 8;
    if (tloc >= Lc && w == 0) {
        float sx = 0.f, sy = 0.f;
#pragma unroll 8
        for (int r = 0; r < 32; ++r) {
            uint u = xt[r][lane];
            sx += bfu((ushort)(u & 0xffffu));
            sy += bfu((ushort)(u >> 16));
        }
        atomicAdd(&mcs[n * C_ + lane * 2], sx);
        atomicAdd(&mcs[n * C_ + lane * 2 + 1], sy);
    }
}

// a-production from xn bf16: conv in registers over 8-t vectors -> logits MFMA
// -> softmax -> a tiles [64k][32t]. Fully-masked blocks return immediately.
__global__ __launch_bounds__(256, 3) void assign2_k(
    const ushort* __restrict__ xtm,
    const float* __restrict__ conv2_b,
    const float* __restrict__ bn2_g, const float* __restrict__ bn2_b,
    const float* __restrict__ bn2_m, const float* __restrict__ bn2_v,
    const int* __restrict__ length,
    const ushort* __restrict__ w2t, const float* __restrict__ p1,
    ushort* __restrict__ agall) {

    __shared__ __align__(16) ushort w2l[8192];
    __shared__ __align__(16) ushort h_s[4][8 * 136];
    __shared__ __align__(16) uint4 ab[2][64 * 5];

    const int tid = threadIdx.x;
    const int lane = tid & 63;
    const int w = tid >> 6;
    const int fr = lane & 15, fg = lane >> 4;
    const int n = blockIdx.x >> 6;
    const int tb = (blockIdx.x & (BPN_A - 1)) * TPB_A;
    const int L = length[n];
    if (tb >= L) return;                   // block-uniform: fully masked

    const ushort* xtm_n = xtm + (size_t)n * 256 * 4096;

    {
        const uint4* w2g = (const uint4*)w2t;
        uint4* w2d = (uint4*)w2l;
#pragma unroll
        for (int i = 0; i < 4; ++i) w2d[tid + i * 256] = w2g[tid + i * 256];
    }

    float wa[2], wbv[2], wcv[2], sbv[2];
#pragma unroll
    for (int p = 0; p < 2; ++p) {
        int c = lane + p * 64;
        wa[p] = p1[c]; wbv[p] = p1[128 + c];
        wcv[p] = p1[256 + c]; sbv[p] = p1[384 + c];
    }

    float sh2r[16];
#pragma unroll
    for (int m = 0; m < 4; ++m)
#pragma unroll
        for (int r = 0; r < 4; ++r) {
            int k = m * 16 + fg * 4 + r;
            float s = bn2_g[k] * rsqrtf(bn2_v[k] + 1e-5f);
            sh2r[m * 4 + r] = s * conv2_b[k] + bn2_b[k] - bn2_m[k] * s;
        }

    ushort* ag = agall + (size_t)n * (T_ / 32) * 2048;
    int buf = 0;
    __syncthreads();

    for (int s = 0; s < TPB_A / 32; ++s) {
        const int tbs = tb + s * 32;
        if (tbs >= L) continue;            // tile fully masked (tail tiles)
        const int tc = tbs >> 5;
        const ushort* xch = xtm_n + (size_t)tc * 4096;
        const int t0 = tbs + w * 8;

        if (t0 < L) {
            // ---- A1: conv from bf16 xn chunks, in registers ----
            ushort* hw = h_s[w];
#pragma unroll
            for (int p = 0; p < 2; ++p) {
                const int c = lane + p * 64;
                short8 xv8 = *(const short8*)&xch[c * 32 + w * 8];
                float xm1 = 0.f, xp8 = 0.f;
                if (t0 > 0)
                    xm1 = bfu(w > 0 ? xch[c * 32 + w * 8 - 1]
                                    : xch[c * 32 + 31 - 4096]);
                if (t0 + 8 < T_)
                    xp8 = bfu(w < 3 ? xch[c * 32 + w * 8 + 8]
                                    : xch[c * 32 + 4096]);
                float a0 = bfu((ushort)xv8[0]), a1 = bfu((ushort)xv8[1]);
                float a2 = bfu((ushort)xv8[2]), a3 = bfu((ushort)xv8[3]);
                float a4 = bfu((ushort)xv8[4]), a5 = bfu((ushort)xv8[5]);
                float a6 = bfu((ushort)xv8[6]), a7 = bfu((ushort)xv8[7]);
                float WA = wa[p], WB = wbv[p], WC = wcv[p], SB = sbv[p];
                hw[0 * 136 + c] = (ushort)bfr(fmaxf(0.f, xm1 * WA + a0 * WB + a1 * WC + SB));
                hw[1 * 136 + c] = (ushort)bfr(fmaxf(0.f, a0 * WA + a1 * WB + a2 * WC + SB));
                hw[2 * 136 + c] = (ushort)bfr(fmaxf(0.f, a1 * WA + a2 * WB + a3 * WC + SB));
                hw[3 * 136 + c] = (ushort)bfr(fmaxf(0.f, a2 * WA + a3 * WB + a4 * WC + SB));
                hw[4 * 136 + c] = (ushort)bfr(fmaxf(0.f, a3 * WA + a4 * WB + a5 * WC + SB));
                hw[5 * 136 + c] = (ushort)bfr(fmaxf(0.f, a4 * WA + a5 * WB + a6 * WC + SB));
                hw[6 * 136 + c] = (ushort)bfr(fmaxf(0.f, a5 * WA + a6 * WB + a7 * WC + SB));
                hw[7 * 136 + c] = (ushort)bfr(fmaxf(0.f, a6 * WA + a7 * WB + xp8 * WC + SB));
            }
            // ---- logits MFMA (w2 from LDS) ----
            f32x4 accL[4];
#pragma unroll
            for (int m = 0; m < 4; ++m) accL[m] = (f32x4){0.f, 0.f, 0.f, 0.f};
            const ushort* hb = h_s[w] + (fr & 7) * 136 + fg * 8;
#pragma unroll
            for (int q = 0; q < 4; ++q) {
                short8 hf = *(const short8*)(hb + q * 32);
                short8 w0 = *(const short8*)&w2l[((0 * 4 + q) * 64 + lane) * 8];
                short8 w1 = *(const short8*)&w2l[((1 * 4 + q) * 64 + lane) * 8];
                short8 w2f = *(const short8*)&w2l[((2 * 4 + q) * 64 + lane) * 8];
                short8 w3 = *(const short8*)&w2l[((3 * 4 + q) * 64 + lane) * 8];
                accL[0] = __builtin_amdgcn_mfma_f32_16x16x32_bf16(w0, hf, accL[0], 0, 0, 0);
                accL[1] = __builtin_amdgcn_mfma_f32_16x16x32_bf16(w1, hf, accL[1], 0, 0, 0);
                accL[2] = __builtin_amdgcn_mfma_f32_16x16x32_bf16(w2f, hf, accL[2], 0, 0, 0);
                accL[3] = __builtin_amdgcn_mfma_f32_16x16x32_bf16(w3, hf, accL[3], 0, 0, 0);
            }
            // ---- bn2 + relu + mask + softmax over k (lane column t = t0+fr, fr<8) ----
            if (fr < 8) {
                int t = t0 + fr;
                float v[16];
#pragma unroll
                for (int m = 0; m < 4; ++m)
#pragma unroll
                    for (int r = 0; r < 4; ++r)
                        v[m * 4 + r] = fmaxf(0.f, accL[m][r] + sh2r[m * 4 + r]);
                if (t < L) {
                    float mx = v[0];
#pragma unroll
                    for (int i = 1; i < 16; ++i) mx = fmaxf(mx, v[i]);
                    mx = fmaxf(mx, __shfl_xor(mx, 16, 64));
                    mx = fmaxf(mx, __shfl_xor(mx, 32, 64));
                    float se = 0.f;
#pragma unroll
                    for (int i = 0; i < 16; ++i) { v[i] = __expf(v[i] - mx); se += v[i]; }
                    se += __shfl_xor(se, 16, 64);
                    se += __shfl_xor(se, 32, 64);
                    float inv = 1.0f / se;
#pragma unroll
                    for (int i = 0; i < 16; ++i) v[i] *= inv;
                } else {
#pragma unroll
                    for (int i = 0; i < 16; ++i) v[i] = 0.015625f;
                }
#pragma unroll
                for (int m = 0; m < 4; ++m)
#pragma unroll
                    for (int r = 0; r < 4; ++r) {
                        int k = m * 16 + fg * 4 + r;
                        ((ushort*)&ab[buf][k * 5 + w])[fr] = (ushort)bfr(v[m * 4 + r]);
                    }
            }
        } else {
            uint4 ones;
            ones.x = ones.y = ones.z = ones.w = 0x3C803C80u;
            ab[buf][lane * 5 + w] = ones;
        }
        __syncthreads();
        {
            uint4 v = ab[buf][(tid >> 2) * 5 + (tid & 3)];
            *((uint4*)(ag + (size_t)(tb / 32 + s) * 2048) + tid) = v;
        }
        buf ^= 1;
    }
}

// barrier-free vlad GEMM over LIVE chunks only (tb < L); masked chunks are
// handled analytically via mcs in finalize2. Boundary masked tiles keep the
// constant-a MFMA path (they are < Lc, so not in mcs).
__global__ __launch_bounds__(256, 4) void vlad2_k(
    const ushort* __restrict__ xtm, const ushort* __restrict__ agall,
    const int* __restrict__ length, float* __restrict__ part,
    float* __restrict__ asum) {

    const int tid = threadIdx.x;
    const int lane = tid & 63;
    const int w = tid >> 6;
    const int fr = lane & 15, fg = lane >> 4;
    const int n = blockIdx.x >> 5;
    const int chunk = blockIdx.x & (NCH - 1);
    const int tb = chunk * TCH;
    const int L = length[n];
    if (tb >= L) return;                   // fully masked chunk: no partials

    const ushort* xn_n = xtm + (size_t)n * 256 * 4096;
    const ushort* ag = agall + (size_t)n * (T_ / 32) * 2048;

    short8 onesf;
    {
        short f = (fr == 0) ? (short)0x3F80 : (short)0;
#pragma unroll
        for (int j = 0; j < 8; ++j) onesf[j] = f;
    }

    f32x4 accB[9];
#pragma unroll
    for (int cb = 0; cb < 9; ++cb) accB[cb] = (f32x4){0.f, 0.f, 0.f, 0.f};

#pragma unroll
    for (int st = 0; st < TCH / 32; ++st) {
        const int t0 = tb + st * 32;
        const int tc = t0 >> 5;
        short8 af;
        if (t0 < L) {
            af = *(const short8*)(ag + (size_t)tc * 2048 + (w * 16 + fr) * 32 + fg * 8);
        } else {
#pragma unroll
            for (int j = 0; j < 8; ++j) af[j] = (short)0x3C80;
        }
        const ushort* xch = xn_n + (size_t)tc * 4096;
#pragma unroll
        for (int cb = 0; cb < 8; ++cb) {
            short8 bfv = *(const short8*)&xch[(cb * 16 + fr) * 32 + fg * 8];
            accB[cb] = __builtin_amdgcn_mfma_f32_16x16x32_bf16(af, bfv, accB[cb], 0, 0, 0);
        }
        accB[8] = __builtin_amdgcn_mfma_f32_16x16x32_bf16(af, onesf, accB[8], 0, 0, 0);
    }

    float* pr = part + (size_t)(n * NCH + chunk) * (K_ * C_);
#pragma unroll
    for (int cb = 0; cb < 8; ++cb)
#pragma unroll
        for (int r = 0; r < 4; ++r)
            pr[(w * 16 + fg * 4 + r) * C_ + cb * 16 + fr] = accB[cb][r];
    if (fr == 0) {
#pragma unroll
        for (int r = 0; r < 4; ++r)
            atomicAdd(&asum[n * K_ + w * 16 + fg * 4 + r], accB[8][r]);
    }
}

// fused reduce + finalize: sum LIVE partials + analytic masked term,
// subtract asum*centroid, intra-normalize, accumulate gsum.
__global__ void finalize2_k(const float* __restrict__ cent,
                            const float* __restrict__ part,
                            const float* __restrict__ asum,
                            const float* __restrict__ mcs,
                            const int* __restrict__ length,
                            float* __restrict__ gsum, float* __restrict__ out) {
    int row = blockIdx.x * 4 + (threadIdx.x >> 6);  // n*64 + k
    int lane = threadIdx.x & 63;
    int n = row >> 6, k = row & 63;
    const int L = length[n];
    const int nlive = (L + 255) >> 8;
    const float* pr = part + (size_t)n * NCH * (K_ * C_) + k * C_;
    float y0 = 0.f, y1 = 0.f;
#pragma unroll 4
    for (int b = 0; b < nlive; ++b) {
        y0 += pr[(size_t)b * (K_ * C_) + lane];
        y1 += pr[(size_t)b * (K_ * C_) + lane + 64];
    }
    // analytic masked-region contribution: a = 1/64 for all k, t in [Lc, T)
    y0 += 0.015625f * mcs[n * C_ + lane];
    y1 += 0.015625f * mcs[n * C_ + lane + 64];
    float as = asum[row] + (float)(T_ - nlive * 256) * 0.015625f;
    y0 -= as * cent[k * C_ + lane];
    y1 -= as * cent[k * C_ + lane + 64];
    float ss = y0 * y0 + y1 * y1;
#pragma unroll
    for (int m = 1; m < 64; m <<= 1) ss += __shfl_xor(ss, m, 64);
    float rs = 1.0f / fmaxf(sqrtf(ss), 1e-12f);
    out[(size_t)row * C_ + lane] = y0 * rs;
    out[(size_t)row * C_ + lane + 64] = y1 * rs;
    if (lane == 0) atomicAdd(&gsum[n], ss * rs * rs);
}

__global__ void gscale2_k(float* __restrict__ out, const float* __restrict__ gsum) {
    int idx = blockIdx.x * 256 + threadIdx.x;
    int n = idx >> 13;
    out[idx] *= 1.0f / fmaxf(sqrtf(gsum[n]), 1e-12f);
}

// ================= OLD (fallback) PATH — proven round-11 kernels ============

__global__ void rnorm_k(const float* __restrict__ x, float* __restrict__ ws) {
    int row = blockIdx.x * 4 + (threadIdx.x >> 6);
    int lane = threadIdx.x & 63;
    const float* xr = x + (size_t)row * C_;
    float a = xr[lane], b = xr[lane + 64];
    float ss = a * a + b * b;
#pragma unroll
    for (int m = 1; m < 64; m <<= 1) ss += __shfl_xor(ss, m, 64);
    if (lane == 0) ws[WS_RNORM + row] = 1.0f / fmaxf(sqrtf(ss), 1e-12f);
}

__global__ __launch_bounds__(256, 3) void assign_k(
    const float* __restrict__ x,
    const float* __restrict__ conv2_b,
    const float* __restrict__ bn2_g, const float* __restrict__ bn2_b,
    const float* __restrict__ bn2_m, const float* __restrict__ bn2_v,
    const int* __restrict__ length,
    float* __restrict__ ws) {

    __shared__ __align__(16) ushort w2l[8192];
    __shared__ __align__(16) ushort h_s[4][8 * 136];
    __shared__ __align__(16) uint4 ab[2][64 * 5];
    __shared__ float rn_lds[TPB_A + 2];

    const int tid = threadIdx.x;
    const int lane = tid & 63;
    const int w = tid >> 6;
    const int fr = lane & 15, fg = lane >> 4;
    const int n = blockIdx.x >> 6;
    const int tb = (blockIdx.x & (BPN_A - 1)) * TPB_A;
    const float* xb = x + (size_t)n * T_ * C_;
    const float* rng = ws + WS_RNORM + (size_t)n * T_;
    const int L = length[n];

    {
        const uint4* w2g = (const uint4*)(ws + WS_W2F);
        uint4* w2d = (uint4*)w2l;
#pragma unroll
        for (int i = 0; i < 4; ++i) w2d[tid + i * 256] = w2g[tid + i * 256];
    }
    for (int i = tid; i < TPB_A + 2; i += 256) {
        int t = tb - 1 + i;
        rn_lds[i] = (t >= 0 && t < T_) ? rng[t] : 0.f;
    }

    const int c2 = lane * 2;
    float2 wa = *(const float2*)&ws[WS_P1 + c2];
    float2 wb = *(const float2*)&ws[WS_P1 + 128 + c2];
    float2 wc = *(const float2*)&ws[WS_P1 + 256 + c2];
    float2 sb = *(const float2*)&ws[WS_P1 + 384 + c2];

    float sh2r[16];
#pragma unroll
    for (int m = 0; m < 4; ++m)
#pragma unroll
        for (int r = 0; r < 4; ++r) {
            int k = m * 16 + fg * 4 + r;
            float s = bn2_g[k] * rsqrtf(bn2_v[k] + 1e-5f);
            sh2r[m * 4 + r] = s * conv2_b[k] + bn2_b[k] - bn2_m[k] * s;
        }

    ushort* ag = (ushort*)(ws + WS_AG) + (size_t)n * T_ * K_;
    int buf = 0;
    __syncthreads();

    for (int s = 0; s < TPB_A / 32; ++s) {
        const int tbs = tb + s * 32;
        if (tbs >= L) continue;
        const int t0 = tbs + w * 8;
        const int tl0 = t0 - tb;

        if (t0 < L) {
            ushort* hw = h_s[w];
            float2 xm = {0.f, 0.f};
            if (t0 > 0) xm = *(const float2*)&xb[(size_t)(t0 - 1) * C_ + c2];
            float rm = rn_lds[tl0];
            float xnmx = xm.x * rm, xnmy = xm.y * rm;
            float2 xc = *(const float2*)&xb[(size_t)t0 * C_ + c2];
            float rc = rn_lds[tl0 + 1];
            float xncx = xc.x * rc, xncy = xc.y * rc;
#pragma unroll
            for (int tl = 0; tl < 8; ++tl) {
                int tn = t0 + tl + 1;
                float2 xp = {0.f, 0.f};
                if (tn < T_) xp = *(const float2*)&xb[(size_t)tn * C_ + c2];
                float rp = rn_lds[tl0 + tl + 2];
                float xnpx = xp.x * rp, xnpy = xp.y * rp;
                float hx = fmaxf(0.f, xnmx * wa.x + xncx * wb.x + xnpx * wc.x + sb.x);
                float hy = fmaxf(0.f, xnmy * wa.y + xncy * wb.y + xnpy * wc.y + sb.y);
                *(uint*)&hw[tl * 136 + c2] = pack2(hx, hy);
                xnmx = xncx; xnmy = xncy; xncx = xnpx; xncy = xnpy;
            }
            f32x4 accL[4];
#pragma unroll
            for (int m = 0; m < 4; ++m) accL[m] = (f32x4){0.f, 0.f, 0.f, 0.f};
            const ushort* hb = hw + (fr & 7) * 136 + fg * 8;
#pragma unroll
            for (int q = 0; q < 4; ++q) {
                short8 hf = *(const short8*)(hb + q * 32);
                short8 w0 = *(const short8*)&w2l[((0 * 4 + q) * 64 + lane) * 8];
                short8 w1 = *(const short8*)&w2l[((1 * 4 + q) * 64 + lane) * 8];
                short8 w2f = *(const short8*)&w2l[((2 * 4 + q) * 64 + lane) * 8];
                short8 w3 = *(const short8*)&w2l[((3 * 4 + q) * 64 + lane) * 8];
                accL[0] = __builtin_amdgcn_mfma_f32_16x16x32_bf16(w0, hf, accL[0], 0, 0, 0);
                accL[1] = __builtin_amdgcn_mfma_f32_16x16x32_bf16(w1, hf, accL[1], 0, 0, 0);
                accL[2] = __builtin_amdgcn_mfma_f32_16x16x32_bf16(w2f, hf, accL[2], 0, 0, 0);
                accL[3] = __builtin_amdgcn_mfma_f32_16x16x32_bf16(w3, hf, accL[3], 0, 0, 0);
            }
            if (fr < 8) {
                int t = t0 + fr;
                float v[16];
#pragma unroll
                for (int m = 0; m < 4; ++m)
#pragma unroll
                    for (int r = 0; r < 4; ++r)
                        v[m * 4 + r] = fmaxf(0.f, accL[m][r] + sh2r[m * 4 + r]);
                if (t < L) {
                    float mx = v[0];
#pragma unroll
                    for (int i = 1; i < 16; ++i) mx = fmaxf(mx, v[i]);
                    mx = fmaxf(mx, __shfl_xor(mx, 16, 64));
                    mx = fmaxf(mx, __shfl_xor(mx, 32, 64));
                    float se = 0.f;
#pragma unroll
                    for (int i = 0; i < 16; ++i) { v[i] = __expf(v[i] - mx); se += v[i]; }
                    se += __shfl_xor(se, 16, 64);
                    se += __shfl_xor(se, 32, 64);
                    float inv = 1.0f / se;
#pragma unroll
                    for (int i = 0; i < 16; ++i) v[i] *= inv;
                } else {
#pragma unroll
                    for (int i = 0; i < 16; ++i) v[i] = 0.015625f;
                }
#pragma unroll
                for (int m = 0; m < 4; ++m)
#pragma unroll
                    for (int r = 0; r < 4; ++r) {
                        int k = m * 16 + fg * 4 + r;
                        ((ushort*)&ab[buf][k * 5 + w])[fr] = (ushort)bfr(v[m * 4 + r]);
                    }
            }
        } else {
            uint4 ones;
            ones.x = ones.y = ones.z = ones.w = 0x3C803C80u;
            ab[buf][lane * 5 + w] = ones;
        }
        __syncthreads();
        {
            uint4 v = ab[buf][(tid >> 2) * 5 + (tid & 3)];
            *((uint4*)(ag + (size_t)(tb / 32 + s) * 2048) + tid) = v;
        }
        buf ^= 1;
    }
}

__global__ __launch_bounds__(256, 4) void vlad_k(
    const float* __restrict__ x, const int* __restrict__ length,
    float* __restrict__ ws) {

    __shared__ __align__(16) uint4 xn4[144 * 5];
    __shared__ float rn_lds[TCH];

    const int tid = threadIdx.x;
    const int lane = tid & 63;
    const int w = tid >> 6;
    const int fr = lane & 15, fg = lane >> 4;
    const int n = blockIdx.x >> 5;
    const int chunk = blockIdx.x & (NCH - 1);
    const int tb = chunk * TCH;
    const float* xb = x + (size_t)n * T_ * C_;
    const float* rng = ws + WS_RNORM + (size_t)n * T_;
    const int L = length[n];

    for (int i = tid; i < TCH; i += 256) rn_lds[i] = rng[tb + i];
    if (tid < 64) {
        int r = 128 + (tid >> 2), j = tid & 3;
        uint f = (r == 128) ? 0x3F803F80u : 0u;
        uint4 v; v.x = f; v.y = f; v.z = f; v.w = f;
        xn4[r * 5 + j] = v;
    }

    const ushort* ag = (const ushort*)(ws + WS_AG) + (size_t)n * T_ * K_;

    f32x4 accB[9];
#pragma unroll
    for (int cb = 0; cb < 9; ++cb) accB[cb] = (f32x4){0.f, 0.f, 0.f, 0.f};

    __syncthreads();

    for (int st = 0; st < TCH / 32; ++st) {
        const int t0 = tb + st * 32;
        const int tw = t0 + w * 8;
#pragma unroll
        for (int p = 0; p < 2; ++p) {
            const int c = lane + p * 64;
            uint pk[4];
#pragma unroll
            for (int tl = 0; tl < 8; ++tl) {
                float xv = xb[(size_t)(tw + tl) * C_ + c] * rn_lds[tw + tl - tb];
                uint b = bfr(xv);
                if (tl & 1) pk[tl >> 1] |= b << 16; else pk[tl >> 1] = b;
            }
            uint4 v4; v4.x = pk[0]; v4.y = pk[1]; v4.z = pk[2]; v4.w = pk[3];
            xn4[c * 5 + w] = v4;
        }
        __syncthreads();
        short8 af;
        if (t0 < L) {
            af = *(const short8*)(ag + (size_t)(t0 >> 5) * 2048 + (w * 16 + fr) * 32 + fg * 8);
        } else {
#pragma unroll
            for (int j = 0; j < 8; ++j) af[j] = (short)0x3C80;
        }
#pragma unroll
        for (int cb = 0; cb < 9; ++cb) {
            short8 bfv = *(const short8*)&xn4[(cb * 16 + fr) * 5 + fg];
            accB[cb] = __builtin_amdgcn_mfma_f32_16x16x32_bf16(af, bfv, accB[cb], 0, 0, 0);
        }
        __syncthreads();
    }

    float* part = ws + WS_PART + (size_t)(n * NCH + chunk) * (K_ * C_);
#pragma unroll
    for (int cb = 0; cb < 8; ++cb)
#pragma unroll
        for (int r = 0; r < 4; ++r)
            part[(w * 16 + fg * 4 + r) * C_ + cb * 16 + fr] = accB[cb][r];
    if (fr == 0) {
#pragma unroll
        for (int r = 0; r < 4; ++r)
            atomicAdd(&ws[WS_ASUM + n * K_ + w * 16 + fg * 4 + r], accB[8][r]);
    }
}

__global__ void reduce_k(float* __restrict__ ws) {
    int idx = blockIdx.x * 256 + threadIdx.x;
    int n = idx >> 13;
    const float* p = ws + WS_PART + (size_t)n * NCH * (K_ * C_) + (idx & 8191);
    float s = 0.f;
#pragma unroll 8
    for (int b = 0; b < NCH; ++b) s += p[(size_t)b * (K_ * C_)];
    ws[WS_VLAD + idx] = s;
}

__global__ void finalize_k(const float* __restrict__ cent, float* __restrict__ ws,
                           float* __restrict__ out) {
    int row = blockIdx.x * 4 + (threadIdx.x >> 6);
    int lane = threadIdx.x & 63;
    int n = row >> 6, k = row & 63;
    const float* v = ws + WS_VLAD + (size_t)row * C_;
    float as = ws[WS_ASUM + row];
    float y0 = v[lane] - as * cent[k * C_ + lane];
    float y1 = v[lane + 64] - as * cent[k * C_ + lane + 64];
    float ss = y0 * y0 + y1 * y1;
#pragma unroll
    for (int m = 1; m < 64; m <<= 1) ss += __shfl_xor(ss, m, 64);
    float rs = 1.0f / fmaxf(sqrtf(ss), 1e-12f);
    out[(size_t)row * C_ + lane] = y0 * rs;
    out[(size_t)row * C_ + lane + 64] = y1 * rs;
    if (lane == 0) atomicAdd(&ws[WS_GSUM + n], ss * rs * rs);
}

extern "C" void kernel_launch(void* const* d_in, const int* in_sizes, int n_in,
                              void* d_out, int out_size, void* d_ws, size_t ws_size,
                              hipStream_t stream) {
    const float* x       = (const float*)d_in[0];
    const float* conv1_w = (const float*)d_in[1];
    const float* bn1_g   = (const float*)d_in[2];
    const float* bn1_b   = (const float*)d_in[3];
    const float* bn1_m   = (const float*)d_in[4];
    const float* bn1_v   = (const float*)d_in[5];
    const float* conv2_w = (const float*)d_in[6];
    const float* conv2_b = (const float*)d_in[7];
    const float* bn2_g   = (const float*)d_in[8];
    const float* bn2_b   = (const float*)d_in[9];
    const float* bn2_m   = (const float*)d_in[10];
    const float* bn2_v   = (const float*)d_in[11];
    const float* cent    = (const float*)d_in[12];
    const int*   length  = (const int*)d_in[13];
    float* out = (float*)d_out;
    float* ws  = (float*)d_ws;

    if (ws_size >= (size_t)NW_TOTAL * 4) {
        // -------- NEW PATH --------
        setup_k<<<4, 256, 0, stream>>>(conv1_w, bn1_g, bn1_b, bn1_m, bn1_v,
                                       conv2_w, bn2_g, bn2_v,
                                       (ushort*)(ws + NW_W2F), ws + NW_P1,
                                       ws, 4096);
        xnorm_k<<<N_ * T_ / 32, 256, 0, stream>>>(x, (ushort*)(ws + NW_XTM),
                                                  length, ws + NW_MCS);
        assign2_k<<<N_ * BPN_A, 256, 0, stream>>>(
            (const ushort*)(ws + NW_XTM), conv2_b, bn2_g, bn2_b, bn2_m, bn2_v,
            length, (const ushort*)(ws + NW_W2F), ws + NW_P1,
            (ushort*)(ws + NW_AG));
        vlad2_k<<<N_ * NCH, 256, 0, stream>>>(
            (const ushort*)(ws + NW_XTM), (const ushort*)(ws + NW_AG),
            length, ws + NW_PART, ws + NW_ASUM);
        finalize2_k<<<(N_ * K_) / 4, 256, 0, stream>>>(
            cent, ws + NW_PART, ws + NW_ASUM, ws + NW_MCS, length,
            ws + NW_GSUM, out);
        gscale2_k<<<(N_ * K_ * C_) / 256, 256, 0, stream>>>(out, ws + NW_GSUM);
    } else {
        // -------- OLD (proven round-11) PATH --------
        setup_k<<<4, 256, 0, stream>>>(conv1_w, bn1_g, bn1_b, bn1_m, bn1_v,
                                       conv2_w, bn2_g, bn2_v,
                                       (ushort*)(ws + WS_W2F), ws + WS_P1,
                                       ws + WS_ASUM, WS_ZEND - WS_ASUM);
        rnorm_k<<<N_ * T_ / 4, 256, 0, stream>>>(x, ws);
        assign_k<<<N_ * BPN_A, 256, 0, stream>>>(x, conv2_b, bn2_g, bn2_b,
                                                 bn2_m, bn2_v, length, ws);
        vlad_k<<<N_ * NCH, 256, 0, stream>>>(x, length, ws);
        reduce_k<<<(N_ * K_ * C_) / 256, 256, 0, stream>>>(ws);
        finalize_k<<<(N_ * K_) / 4, 256, 0, stream>>>(cent, ws, out);
        gscale2_k<<<(N_ * K_ * C_) / 256, 256, 0, stream>>>(out, ws + WS_GSUM);
    }
}

// Round 14
// 87.308 us; speedup vs baseline: 1.1203x; 1.1203x over previous
//
#include <hip/hip_runtime.h>
#include <math.h>

#define N_ 16
#define T_ 8192
#define C_ 128
#define K_ 64

#define TPB_A 128      // t per assign block
#define BPN_A 64       // assign blocks per n
#define TCH 256        // t per vlad block
#define NCH 32         // vlad chunks per n

// ws layout in floats (67.15 MB; ws proven 268 MB by harness poison fills)
#define NW_ASUM 0              // 1024
#define NW_GSUM 1024           // 16
#define NW_MCS  2048           // N*C = 2048 -> 4096  (masked colsum)
#define NW_W2F  4096           // 4096 floats (8192 bf16)
#define NW_P1   8192           // 512 -> 8704
#define NW_XTM  8960           // N*T*C bf16 = 8388608 floats -> 8397568
#define NW_AG   8397568        // N*T*K bf16 = 4194304 floats -> 12591872
#define NW_PART 12591872       // N*NCH*K*C  = 4194304 floats -> 16786176
#define NW_TOTAL 16786176

typedef __attribute__((ext_vector_type(8))) short short8;
typedef __attribute__((ext_vector_type(4))) float f32x4;

__device__ __forceinline__ uint bfr(float f) {          // fp32 -> bf16 (RNE)
    uint u = __float_as_uint(f);
    return (u + 0x7fffu + ((u >> 16) & 1u)) >> 16;
}
__device__ __forceinline__ uint pack2(float lo, float hi) {
    return bfr(lo) | (bfr(hi) << 16);
}
__device__ __forceinline__ float bfu(ushort u) {
    return __uint_as_float(((uint)u) << 16);
}

// Precompute constant tables + zero the accumulator region. grid = 4 blocks.
__global__ void setup_k(const float* __restrict__ conv1_w,
                        const float* __restrict__ bn1_g, const float* __restrict__ bn1_b,
                        const float* __restrict__ bn1_m, const float* __restrict__ bn1_v,
                        const float* __restrict__ conv2_w,
                        const float* __restrict__ bn2_g, const float* __restrict__ bn2_v,
                        ushort* __restrict__ w2t, float* __restrict__ p1,
                        float* __restrict__ zr, int zcnt) {
    const int gt = blockIdx.x * 256 + threadIdx.x;   // 0..1023
    for (int idx = gt; idx < 8192; idx += 1024) {
        int j = idx & 7;
        int lane = (idx >> 3) & 63;
        int mq = idx >> 9;
        int m = mq >> 2, q = mq & 3;
        int fr = lane & 15, fg = lane >> 4;
        int k = m * 16 + fr;
        float sck = bn2_g[k] * rsqrtf(bn2_v[k] + 1e-5f);
        float v = conv2_w[k * C_ + q * 32 + fg * 8 + j] * sck;
        w2t[idx] = (ushort)bfr(v);
    }
    for (int c = gt; c < C_; c += 1024) {
        float s1 = bn1_g[c] * rsqrtf(bn1_v[c] + 1e-5f);
        p1[c]       = conv1_w[c * 9 + 1] * s1;
        p1[128 + c] = conv1_w[c * 9 + 4] * s1;
        p1[256 + c] = conv1_w[c * 9 + 7] * s1;
        p1[384 + c] = bn1_b[c] - bn1_m[c] * s1;
    }
    for (int i = gt; i < zcnt; i += 1024) zr[i] = 0.0f;
}

// Normalize rows, emit xn bf16 t-minor chunks [chunk=32t][128c][32t] (live
// chunks only: tloc <= Lc), and accumulate masked-region colsum into mcs.
__global__ __launch_bounds__(256, 8) void xnorm_k(const float* __restrict__ x,
                                                  ushort* __restrict__ xtm,
                                                  const int* __restrict__ length,
                                                  float* __restrict__ mcs) {
    __shared__ uint xt[32][64];            // packed c-pairs, [t][c2]
    const int tid = threadIdx.x;
    const int lane = tid & 63;
    const int w = tid >> 6;
    const int n = blockIdx.x >> 8;
    const int tloc = (blockIdx.x & 255) * 32;
    const size_t row0 = (size_t)blockIdx.x * 32;
    const int L = length[n];
    const int Lc = ((L + 255) >> 8) << 8;

#pragma unroll
    for (int i = 0; i < 8; ++i) {
        int r = w * 8 + i;
        const float* xr = x + (row0 + r) * C_;
        float2 v = *(const float2*)&xr[lane * 2];
        float ss = v.x * v.x + v.y * v.y;
#pragma unroll
        for (int m = 1; m < 64; m <<= 1) ss += __shfl_xor(ss, m, 64);
        float rn = 1.0f / fmaxf(sqrtf(ss), 1e-12f);
        xt[r][lane] = pack2(v.x * rn, v.y * rn);
    }
    __syncthreads();

    if (tloc <= Lc) {
        // consumed by assign (up to chunk Lc/32) and vlad (< Lc): store it
        uint4* dst = (uint4*)(xtm + (size_t)blockIdx.x * 4096);
#pragma unroll
        for (int uu = 0; uu < 2; ++uu) {
            int u = tid * 2 + uu;              // 0..511
            int c = u >> 2, j = u & 3;
            int cw = c >> 1, sh = (c & 1) * 16;
            uint o[4];
#pragma unroll
            for (int q = 0; q < 4; ++q) {
                uint lo = (xt[j * 8 + q * 2][cw] >> sh) & 0xffffu;
                uint hi = (xt[j * 8 + q * 2 + 1][cw] >> sh) & 0xffffu;
                o[q] = lo | (hi << 16);
            }
            uint4 v; v.x = o[0]; v.y = o[1]; v.z = o[2]; v.w = o[3];
            dst[u] = v;
        }
    }
    if (tloc >= Lc && w == 0) {
        // masked-region colsum: vlad skips chunks >= Lc; contribution = mcs/64
        float sx = 0.f, sy = 0.f;
#pragma unroll 8
        for (int r = 0; r < 32; ++r) {
            uint u = xt[r][lane];
            sx += bfu((ushort)(u & 0xffffu));
            sy += bfu((ushort)(u >> 16));
        }
        atomicAdd(&mcs[n * C_ + lane * 2], sx);
        atomicAdd(&mcs[n * C_ + lane * 2 + 1], sy);
    }
}

// a-production, TILE=16: wave (tile=w>>1, half=w&1) owns 16 real t.
// conv in registers -> logits MFMA (all 16 B-columns real) -> softmax on all
// 64 lanes -> a tiles [64k][32t] to global. Masked blocks/tiles skipped.
__global__ __launch_bounds__(256, 3) void assign2_k(
    const ushort* __restrict__ xtm,
    const float* __restrict__ conv2_b,
    const float* __restrict__ bn2_g, const float* __restrict__ bn2_b,
    const float* __restrict__ bn2_m, const float* __restrict__ bn2_v,
    const int* __restrict__ length,
    const ushort* __restrict__ w2t, const float* __restrict__ p1,
    ushort* __restrict__ agall) {

    __shared__ __align__(16) ushort w2l[8192];           // 16 KB
    __shared__ __align__(16) ushort h_s[4][16 * 136];    // 17.4 KB
    __shared__ __align__(16) uint4 ab[2][64 * 5];        // 10 KB (2 tiles/ST)

    const int tid = threadIdx.x;
    const int lane = tid & 63;
    const int w = tid >> 6;
    const int fr = lane & 15, fg = lane >> 4;
    const int tile = w >> 1, half = w & 1;
    const int n = blockIdx.x >> 6;
    const int tb = (blockIdx.x & (BPN_A - 1)) * TPB_A;
    const int L = length[n];
    if (tb >= L) return;                   // block-uniform: fully masked

    const ushort* xtm_n = xtm + (size_t)n * 256 * 4096;

    {
        const uint4* w2g = (const uint4*)w2t;
        uint4* w2d = (uint4*)w2l;
#pragma unroll
        for (int i = 0; i < 4; ++i) w2d[tid + i * 256] = w2g[tid + i * 256];
    }

    float wa[2], wbv[2], wcv[2], sbv[2];
#pragma unroll
    for (int p = 0; p < 2; ++p) {
        int c = lane + p * 64;
        wa[p] = p1[c]; wbv[p] = p1[128 + c];
        wcv[p] = p1[256 + c]; sbv[p] = p1[384 + c];
    }

    float sh2r[16];
#pragma unroll
    for (int m = 0; m < 4; ++m)
#pragma unroll
        for (int r = 0; r < 4; ++r) {
            int k = m * 16 + fg * 4 + r;
            float s = bn2_g[k] * rsqrtf(bn2_v[k] + 1e-5f);
            sh2r[m * 4 + r] = s * conv2_b[k] + bn2_b[k] - bn2_m[k] * s;
        }

    ushort* ag = agall + (size_t)n * (T_ / 32) * 2048;
    __syncthreads();

    for (int s = 0; s < TPB_A / 64; ++s) {
        const int tbs = tb + s * 64;
        if (tbs >= L) continue;            // ST fully masked (block-uniform)
        const int tcs = (tbs >> 5) + tile;
        const ushort* xch = xtm_n + (size_t)tcs * 4096;
        const int t0 = tbs + tile * 32 + half * 16;

        if (t0 < L) {
            // ---- conv: lane owns c = lane, lane+64; 16 t in registers ----
            ushort* hw = h_s[w];
#pragma unroll
            for (int p = 0; p < 2; ++p) {
                const int c = lane + p * 64;
                short8 x0 = *(const short8*)&xch[c * 32 + half * 16];
                short8 x1 = *(const short8*)&xch[c * 32 + half * 16 + 8];
                float av[18];
                av[0] = 0.f; av[17] = 0.f;
                if (t0 > 0)
                    av[0] = bfu(half ? xch[c * 32 + 15] : xch[c * 32 - 4096 + 31]);
                if (t0 + 16 < T_)
                    av[17] = bfu(half ? xch[c * 32 + 4096] : xch[c * 32 + 16]);
#pragma unroll
                for (int j = 0; j < 8; ++j) {
                    av[1 + j] = bfu((ushort)x0[j]);
                    av[9 + j] = bfu((ushort)x1[j]);
                }
                float WA = wa[p], WB = wbv[p], WC = wcv[p], SB = sbv[p];
#pragma unroll
                for (int j = 0; j < 16; ++j)
                    hw[j * 136 + c] = (ushort)bfr(
                        fmaxf(0.f, av[j] * WA + av[j + 1] * WB + av[j + 2] * WC + SB));
            }
            // ---- logits MFMA (w2 from LDS; all 16 B-columns real) ----
            f32x4 accL[4];
#pragma unroll
            for (int m = 0; m < 4; ++m) accL[m] = (f32x4){0.f, 0.f, 0.f, 0.f};
            const ushort* hbp = h_s[w] + fr * 136 + fg * 8;
#pragma unroll
            for (int q = 0; q < 4; ++q) {
                short8 hf = *(const short8*)(hbp + q * 32);
                short8 w0 = *(const short8*)&w2l[((0 * 4 + q) * 64 + lane) * 8];
                short8 w1 = *(const short8*)&w2l[((1 * 4 + q) * 64 + lane) * 8];
                short8 w2f = *(const short8*)&w2l[((2 * 4 + q) * 64 + lane) * 8];
                short8 w3 = *(const short8*)&w2l[((3 * 4 + q) * 64 + lane) * 8];
                accL[0] = __builtin_amdgcn_mfma_f32_16x16x32_bf16(w0, hf, accL[0], 0, 0, 0);
                accL[1] = __builtin_amdgcn_mfma_f32_16x16x32_bf16(w1, hf, accL[1], 0, 0, 0);
                accL[2] = __builtin_amdgcn_mfma_f32_16x16x32_bf16(w2f, hf, accL[2], 0, 0, 0);
                accL[3] = __builtin_amdgcn_mfma_f32_16x16x32_bf16(w3, hf, accL[3], 0, 0, 0);
            }
            // ---- bn2 + relu + mask + softmax over k (t = t0 + fr, all lanes) ----
            {
                int t = t0 + fr;
                float v[16];
#pragma unroll
                for (int m = 0; m < 4; ++m)
#pragma unroll
                    for (int r = 0; r < 4; ++r)
                        v[m * 4 + r] = fmaxf(0.f, accL[m][r] + sh2r[m * 4 + r]);
                if (t < L) {
                    float mx = v[0];
#pragma unroll
                    for (int i = 1; i < 16; ++i) mx = fmaxf(mx, v[i]);
                    mx = fmaxf(mx, __shfl_xor(mx, 16, 64));
                    mx = fmaxf(mx, __shfl_xor(mx, 32, 64));
                    float se = 0.f;
#pragma unroll
                    for (int i = 0; i < 16; ++i) { v[i] = __expf(v[i] - mx); se += v[i]; }
                    se += __shfl_xor(se, 16, 64);
                    se += __shfl_xor(se, 32, 64);
                    float inv = 1.0f / se;
#pragma unroll
                    for (int i = 0; i < 16; ++i) v[i] *= inv;
                } else {
#pragma unroll
                    for (int i = 0; i < 16; ++i) v[i] = 0.015625f;
                }
                const int jq = half * 2 + (fr >> 3);
                const int te = fr & 7;
#pragma unroll
                for (int m = 0; m < 4; ++m)
#pragma unroll
                    for (int r = 0; r < 4; ++r) {
                        int k = m * 16 + fg * 4 + r;
                        ((ushort*)&ab[tile][k * 5 + jq])[te] = (ushort)bfr(v[m * 4 + r]);
                    }
            }
        } else {
            // wave-masked within a live ST: a = 1/64 exactly (2 chunks)
            uint4 ones;
            ones.x = ones.y = ones.z = ones.w = 0x3C803C80u;
            ab[tile][lane * 5 + half * 2] = ones;
            ab[tile][lane * 5 + half * 2 + 1] = ones;
        }
        __syncthreads();
        // ---- copy-out both a tiles [64k][32t] (2 x 4 KB, coalesced) ----
#pragma unroll
        for (int tt = 0; tt < 2; ++tt) {
            uint4 v = ab[tt][(tid >> 2) * 5 + (tid & 3)];
            *((uint4*)(ag + (size_t)(tbs / 32 + tt) * 2048) + tid) = v;
        }
        __syncthreads();
    }
}

// barrier-free vlad GEMM over LIVE chunks only; masked chunks analytic (mcs).
__global__ __launch_bounds__(256, 4) void vlad2_k(
    const ushort* __restrict__ xtm, const ushort* __restrict__ agall,
    const int* __restrict__ length, float* __restrict__ part,
    float* __restrict__ asum) {

    const int tid = threadIdx.x;
    const int lane = tid & 63;
    const int w = tid >> 6;
    const int fr = lane & 15, fg = lane >> 4;
    const int n = blockIdx.x >> 5;
    const int chunk = blockIdx.x & (NCH - 1);
    const int tb = chunk * TCH;
    const int L = length[n];
    if (tb >= L) return;                   // fully masked chunk: no partials

    const ushort* xn_n = xtm + (size_t)n * 256 * 4096;
    const ushort* ag = agall + (size_t)n * (T_ / 32) * 2048;

    short8 onesf;
    {
        short f = (fr == 0) ? (short)0x3F80 : (short)0;
#pragma unroll
        for (int j = 0; j < 8; ++j) onesf[j] = f;
    }

    f32x4 accB[9];
#pragma unroll
    for (int cb = 0; cb < 9; ++cb) accB[cb] = (f32x4){0.f, 0.f, 0.f, 0.f};

#pragma unroll
    for (int st = 0; st < TCH / 32; ++st) {
        const int t0 = tb + st * 32;
        const int tc = t0 >> 5;
        short8 af;
        if (t0 < L) {
            af = *(const short8*)(ag + (size_t)tc * 2048 + (w * 16 + fr) * 32 + fg * 8);
        } else {
#pragma unroll
            for (int j = 0; j < 8; ++j) af[j] = (short)0x3C80;
        }
        const ushort* xch = xn_n + (size_t)tc * 4096;
#pragma unroll
        for (int cb = 0; cb < 8; ++cb) {
            short8 bfv = *(const short8*)&xch[(cb * 16 + fr) * 32 + fg * 8];
            accB[cb] = __builtin_amdgcn_mfma_f32_16x16x32_bf16(af, bfv, accB[cb], 0, 0, 0);
        }
        accB[8] = __builtin_amdgcn_mfma_f32_16x16x32_bf16(af, onesf, accB[8], 0, 0, 0);
    }

    float* pr = part + (size_t)(n * NCH + chunk) * (K_ * C_);
#pragma unroll
    for (int cb = 0; cb < 8; ++cb)
#pragma unroll
        for (int r = 0; r < 4; ++r)
            pr[(w * 16 + fg * 4 + r) * C_ + cb * 16 + fr] = accB[cb][r];
    if (fr == 0) {
#pragma unroll
        for (int r = 0; r < 4; ++r)
            atomicAdd(&asum[n * K_ + w * 16 + fg * 4 + r], accB[8][r]);
    }
}

// fused reduce + finalize: live partials + analytic masked term, intra-norm.
__global__ void finalize2_k(const float* __restrict__ cent,
                            const float* __restrict__ part,
                            const float* __restrict__ asum,
                            const float* __restrict__ mcs,
                            const int* __restrict__ length,
                            float* __restrict__ gsum, float* __restrict__ out) {
    int row = blockIdx.x * 4 + (threadIdx.x >> 6);  // n*64 + k
    int lane = threadIdx.x & 63;
    int n = row >> 6, k = row & 63;
    const int L = length[n];
    const int nlive = (L + 255) >> 8;
    const float* pr = part + (size_t)n * NCH * (K_ * C_) + k * C_;
    float y0 = 0.f, y1 = 0.f;
#pragma unroll 4
    for (int b = 0; b < nlive; ++b) {
        y0 += pr[(size_t)b * (K_ * C_) + lane];
        y1 += pr[(size_t)b * (K_ * C_) + lane + 64];
    }
    y0 += 0.015625f * mcs[n * C_ + lane];
    y1 += 0.015625f * mcs[n * C_ + lane + 64];
    float as = asum[row] + (float)(T_ - nlive * 256) * 0.015625f;
    y0 -= as * cent[k * C_ + lane];
    y1 -= as * cent[k * C_ + lane + 64];
    float ss = y0 * y0 + y1 * y1;
#pragma unroll
    for (int m = 1; m < 64; m <<= 1) ss += __shfl_xor(ss, m, 64);
    float rs = 1.0f / fmaxf(sqrtf(ss), 1e-12f);
    out[(size_t)row * C_ + lane] = y0 * rs;
    out[(size_t)row * C_ + lane + 64] = y1 * rs;
    if (lane == 0) atomicAdd(&gsum[n], ss * rs * rs);
}

__global__ void gscale2_k(float* __restrict__ out, const float* __restrict__ gsum) {
    int idx = blockIdx.x * 256 + threadIdx.x;
    int n = idx >> 13;
    out[idx] *= 1.0f / fmaxf(sqrtf(gsum[n]), 1e-12f);
}

extern "C" void kernel_launch(void* const* d_in, const int* in_sizes, int n_in,
                              void* d_out, int out_size, void* d_ws, size_t ws_size,
                              hipStream_t stream) {
    const float* x       = (const float*)d_in[0];
    const float* conv1_w = (const float*)d_in[1];
    const float* bn1_g   = (const float*)d_in[2];
    const float* bn1_b   = (const float*)d_in[3];
    const float* bn1_m   = (const float*)d_in[4];
    const float* bn1_v   = (const float*)d_in[5];
    const float* conv2_w = (const float*)d_in[6];
    const float* conv2_b = (const float*)d_in[7];
    const float* bn2_g   = (const float*)d_in[8];
    const float* bn2_b   = (const float*)d_in[9];
    const float* bn2_m   = (const float*)d_in[10];
    const float* bn2_v   = (const float*)d_in[11];
    const float* cent    = (const float*)d_in[12];
    const int*   length  = (const int*)d_in[13];
    float* out = (float*)d_out;
    float* ws  = (float*)d_ws;

    setup_k<<<4, 256, 0, stream>>>(conv1_w, bn1_g, bn1_b, bn1_m, bn1_v,
                                   conv2_w, bn2_g, bn2_v,
                                   (ushort*)(ws + NW_W2F), ws + NW_P1,
                                   ws, 4096);
    xnorm_k<<<N_ * T_ / 32, 256, 0, stream>>>(x, (ushort*)(ws + NW_XTM),
                                              length, ws + NW_MCS);
    assign2_k<<<N_ * BPN_A, 256, 0, stream>>>(
        (const ushort*)(ws + NW_XTM), conv2_b, bn2_g, bn2_b, bn2_m, bn2_v,
        length, (const ushort*)(ws + NW_W2F), ws + NW_P1,
        (ushort*)(ws + NW_AG));
    vlad2_k<<<N_ * NCH, 256, 0, stream>>>(
        (const ushort*)(ws + NW_XTM), (const ushort*)(ws + NW_AG),
        length, ws + NW_PART, ws + NW_ASUM);
    finalize2_k<<<(N_ * K_) / 4, 256, 0, stream>>>(
        cent, ws + NW_PART, ws + NW_ASUM, ws + NW_MCS, length,
        ws + NW_GSUM, out);
    gscale2_k<<<(N_ * K_ * C_) / 256, 256, 0, stream>>>(out, ws + NW_GSUM);
}

// Round 15
// 80.847 us; speedup vs baseline: 1.2098x; 1.0799x over previous
//
#include <hip/hip_runtime.h>
#include <math.h>

#define N_ 16
#define T_ 8192
#define C_ 128
#define K_ 64

#define TPB_A 128      // t per fused block
#define BPN_A 64       // fused blocks per n

// ws layout in floats (67.15 MB; ws proven 268 MB by harness poison fills)
#define NW_ASUM 0              // 1024
#define NW_GSUM 1024           // 16
#define NW_MCS  2048           // N*C = 2048 -> 4096  (masked colsum)
#define NW_W2F  4096           // 4096 floats (8192 bf16)
#define NW_P1   8192           // 512 -> 8704, pad to 8960
#define NW_XTM  8960           // N*T*C bf16 = 8388608 floats -> 8397568
#define NW_PART 8397568        // N*BPN_A*K*C = 8388608 floats -> 16786176
#define NW_TOTAL 16786176

typedef __attribute__((ext_vector_type(8))) short short8;
typedef __attribute__((ext_vector_type(4))) float f32x4;

__device__ __forceinline__ uint bfr(float f) {          // fp32 -> bf16 (RNE)
    uint u = __float_as_uint(f);
    return (u + 0x7fffu + ((u >> 16) & 1u)) >> 16;
}
__device__ __forceinline__ uint pack2(float lo, float hi) {
    return bfr(lo) | (bfr(hi) << 16);
}
__device__ __forceinline__ float bfu(ushort u) {
    return __uint_as_float(((uint)u) << 16);
}

// Precompute constant tables + zero the accumulator region. grid = 4 blocks.
__global__ void setup_k(const float* __restrict__ conv1_w,
                        const float* __restrict__ bn1_g, const float* __restrict__ bn1_b,
                        const float* __restrict__ bn1_m, const float* __restrict__ bn1_v,
                        const float* __restrict__ conv2_w,
                        const float* __restrict__ bn2_g, const float* __restrict__ bn2_v,
                        ushort* __restrict__ w2t, float* __restrict__ p1,
                        float* __restrict__ zr, int zcnt) {
    const int gt = blockIdx.x * 256 + threadIdx.x;   // 0..1023
    for (int idx = gt; idx < 8192; idx += 1024) {
        int j = idx & 7;
        int lane = (idx >> 3) & 63;
        int mq = idx >> 9;
        int m = mq >> 2, q = mq & 3;
        int fr = lane & 15, fg = lane >> 4;
        int k = m * 16 + fr;
        float sck = bn2_g[k] * rsqrtf(bn2_v[k] + 1e-5f);
        float v = conv2_w[k * C_ + q * 32 + fg * 8 + j] * sck;
        w2t[idx] = (ushort)bfr(v);
    }
    for (int c = gt; c < C_; c += 1024) {
        float s1 = bn1_g[c] * rsqrtf(bn1_v[c] + 1e-5f);
        p1[c]       = conv1_w[c * 9 + 1] * s1;
        p1[128 + c] = conv1_w[c * 9 + 4] * s1;
        p1[256 + c] = conv1_w[c * 9 + 7] * s1;
        p1[384 + c] = bn1_b[c] - bn1_m[c] * s1;
    }
    for (int i = gt; i < zcnt; i += 1024) zr[i] = 0.0f;
}

// Normalize rows, emit xn bf16 t-minor chunks [chunk=32t][128c][32t] (chunks
// up to Lb + halo), and accumulate masked-region (t >= Lb) colsum into mcs.
__global__ __launch_bounds__(256, 8) void xnorm_k(const float* __restrict__ x,
                                                  ushort* __restrict__ xtm,
                                                  const int* __restrict__ length,
                                                  float* __restrict__ mcs) {
    __shared__ uint xt[32][64];            // packed c-pairs, [t][c2]
    const int tid = threadIdx.x;
    const int lane = tid & 63;
    const int w = tid >> 6;
    const int n = blockIdx.x >> 8;
    const int tloc = (blockIdx.x & 255) * 32;
    const size_t row0 = (size_t)blockIdx.x * 32;
    const int L = length[n];
    const int Lb = ((L + 127) >> 7) << 7;  // live-block coverage [0, Lb)

#pragma unroll
    for (int i = 0; i < 8; ++i) {
        int r = w * 8 + i;
        const float* xr = x + (row0 + r) * C_;
        float2 v = *(const float2*)&xr[lane * 2];
        float ss = v.x * v.x + v.y * v.y;
#pragma unroll
        for (int m = 1; m < 64; m <<= 1) ss += __shfl_xor(ss, m, 64);
        float rn = 1.0f / fmaxf(sqrtf(ss), 1e-12f);
        xt[r][lane] = pack2(v.x * rn, v.y * rn);
    }
    __syncthreads();

    if (tloc <= Lb) {
        // consumed by fused kernel (conv halo reaches chunk Lb/32): store it
        uint4* dst = (uint4*)(xtm + (size_t)blockIdx.x * 4096);
#pragma unroll
        for (int uu = 0; uu < 2; ++uu) {
            int u = tid * 2 + uu;              // 0..511
            int c = u >> 2, j = u & 3;
            int cw = c >> 1, sh = (c & 1) * 16;
            uint o[4];
#pragma unroll
            for (int q = 0; q < 4; ++q) {
                uint lo = (xt[j * 8 + q * 2][cw] >> sh) & 0xffffu;
                uint hi = (xt[j * 8 + q * 2 + 1][cw] >> sh) & 0xffffu;
                o[q] = lo | (hi << 16);
            }
            uint4 v; v.x = o[0]; v.y = o[1]; v.z = o[2]; v.w = o[3];
            dst[u] = v;
        }
    }
    if (tloc >= Lb && w == 0) {
        // analytic masked region [Lb, T): contribution = mcs/64
        float sx = 0.f, sy = 0.f;
#pragma unroll 8
        for (int r = 0; r < 32; ++r) {
            uint u = xt[r][lane];
            sx += bfu((ushort)(u & 0xffffu));
            sy += bfu((ushort)(u >> 16));
        }
        atomicAdd(&mcs[n * C_ + lane * 2], sx);
        atomicAdd(&mcs[n * C_ + lane * 2 + 1], sy);
    }
}

// Fused: conv -> logits MFMA -> softmax -> a in LDS -> vlad MFMA (af from LDS,
// bfv from xtm/L2) -> private partials. Blocks with tb >= L return early.
__global__ __launch_bounds__(256, 3) void fused_k(
    const ushort* __restrict__ xtm,
    const float* __restrict__ conv2_b,
    const float* __restrict__ bn2_g, const float* __restrict__ bn2_b,
    const float* __restrict__ bn2_m, const float* __restrict__ bn2_v,
    const int* __restrict__ length,
    const ushort* __restrict__ w2t, const float* __restrict__ p1,
    float* __restrict__ part, float* __restrict__ asum) {

    __shared__ __align__(16) ushort w2l[8192];           // 16 KB
    __shared__ __align__(16) ushort h_s[4][16 * 136];    // 17.4 KB
    __shared__ __align__(16) uint4 ab[2][64 * 5];        // 10.2 KB

    const int tid = threadIdx.x;
    const int lane = tid & 63;
    const int w = tid >> 6;
    const int fr = lane & 15, fg = lane >> 4;
    const int tile = w >> 1, half = w & 1;
    const int n = blockIdx.x >> 6;
    const int blk = blockIdx.x & (BPN_A - 1);
    const int tb = blk * TPB_A;
    const int L = length[n];
    if (tb >= L) return;                   // analytic region (mcs)

    const ushort* xtm_n = xtm + (size_t)n * 256 * 4096;

    {
        const uint4* w2g = (const uint4*)w2t;
        uint4* w2d = (uint4*)w2l;
#pragma unroll
        for (int i = 0; i < 4; ++i) w2d[tid + i * 256] = w2g[tid + i * 256];
    }

    float wa[2], wbv[2], wcv[2], sbv[2];
#pragma unroll
    for (int p = 0; p < 2; ++p) {
        int c = lane + p * 64;
        wa[p] = p1[c]; wbv[p] = p1[128 + c];
        wcv[p] = p1[256 + c]; sbv[p] = p1[384 + c];
    }

    float sh2r[16];
#pragma unroll
    for (int m = 0; m < 4; ++m)
#pragma unroll
        for (int r = 0; r < 4; ++r) {
            int k = m * 16 + fg * 4 + r;
            float s = bn2_g[k] * rsqrtf(bn2_v[k] + 1e-5f);
            sh2r[m * 4 + r] = s * conv2_b[k] + bn2_b[k] - bn2_m[k] * s;
        }

    short8 onesf;
    {
        short f = (fr == 0) ? (short)0x3F80 : (short)0;
#pragma unroll
        for (int j = 0; j < 8; ++j) onesf[j] = f;
    }

    f32x4 accB[9];
#pragma unroll
    for (int cb = 0; cb < 9; ++cb) accB[cb] = (f32x4){0.f, 0.f, 0.f, 0.f};

    __syncthreads();

    for (int s = 0; s < TPB_A / 64; ++s) {
        const int tbs = tb + s * 64;
        const int tcs = (tbs >> 5) + tile;
        const ushort* xch = xtm_n + (size_t)tcs * 4096;
        const int t0 = tbs + tile * 32 + half * 16;

        if (t0 < L) {
            // ---- conv: lane owns c = lane, lane+64; 16 t in registers ----
            ushort* hw = h_s[w];
#pragma unroll
            for (int p = 0; p < 2; ++p) {
                const int c = lane + p * 64;
                short8 x0 = *(const short8*)&xch[c * 32 + half * 16];
                short8 x1 = *(const short8*)&xch[c * 32 + half * 16 + 8];
                float av[18];
                av[0] = 0.f; av[17] = 0.f;
                if (t0 > 0)
                    av[0] = bfu(half ? xch[c * 32 + 15] : xch[c * 32 - 4096 + 31]);
                if (t0 + 16 < T_)
                    av[17] = bfu(half ? xch[c * 32 + 4096] : xch[c * 32 + 16]);
#pragma unroll
                for (int j = 0; j < 8; ++j) {
                    av[1 + j] = bfu((ushort)x0[j]);
                    av[9 + j] = bfu((ushort)x1[j]);
                }
                float WA = wa[p], WB = wbv[p], WC = wcv[p], SB = sbv[p];
#pragma unroll
                for (int j = 0; j < 16; ++j)
                    hw[j * 136 + c] = (ushort)bfr(
                        fmaxf(0.f, av[j] * WA + av[j + 1] * WB + av[j + 2] * WC + SB));
            }
            // ---- logits MFMA (w2 from LDS; all 16 B-columns real) ----
            f32x4 accL[4];
#pragma unroll
            for (int m = 0; m < 4; ++m) accL[m] = (f32x4){0.f, 0.f, 0.f, 0.f};
            const ushort* hbp = h_s[w] + fr * 136 + fg * 8;
#pragma unroll
            for (int q = 0; q < 4; ++q) {
                short8 hf = *(const short8*)(hbp + q * 32);
                short8 w0 = *(const short8*)&w2l[((0 * 4 + q) * 64 + lane) * 8];
                short8 w1 = *(const short8*)&w2l[((1 * 4 + q) * 64 + lane) * 8];
                short8 w2f = *(const short8*)&w2l[((2 * 4 + q) * 64 + lane) * 8];
                short8 w3 = *(const short8*)&w2l[((3 * 4 + q) * 64 + lane) * 8];
                accL[0] = __builtin_amdgcn_mfma_f32_16x16x32_bf16(w0, hf, accL[0], 0, 0, 0);
                accL[1] = __builtin_amdgcn_mfma_f32_16x16x32_bf16(w1, hf, accL[1], 0, 0, 0);
                accL[2] = __builtin_amdgcn_mfma_f32_16x16x32_bf16(w2f, hf, accL[2], 0, 0, 0);
                accL[3] = __builtin_amdgcn_mfma_f32_16x16x32_bf16(w3, hf, accL[3], 0, 0, 0);
            }
            // ---- bn2 + relu + mask + softmax over k (t = t0 + fr, all lanes) ----
            {
                int t = t0 + fr;
                float v[16];
#pragma unroll
                for (int m = 0; m < 4; ++m)
#pragma unroll
                    for (int r = 0; r < 4; ++r)
                        v[m * 4 + r] = fmaxf(0.f, accL[m][r] + sh2r[m * 4 + r]);
                if (t < L) {
                    float mx = v[0];
#pragma unroll
                    for (int i = 1; i < 16; ++i) mx = fmaxf(mx, v[i]);
                    mx = fmaxf(mx, __shfl_xor(mx, 16, 64));
                    mx = fmaxf(mx, __shfl_xor(mx, 32, 64));
                    float se = 0.f;
#pragma unroll
                    for (int i = 0; i < 16; ++i) { v[i] = __expf(v[i] - mx); se += v[i]; }
                    se += __shfl_xor(se, 16, 64);
                    se += __shfl_xor(se, 32, 64);
                    float inv = 1.0f / se;
#pragma unroll
                    for (int i = 0; i < 16; ++i) v[i] *= inv;
                } else {
#pragma unroll
                    for (int i = 0; i < 16; ++i) v[i] = 0.015625f;
                }
                const int jq = half * 2 + (fr >> 3);
                const int te = fr & 7;
#pragma unroll
                for (int m = 0; m < 4; ++m)
#pragma unroll
                    for (int r = 0; r < 4; ++r) {
                        int k = m * 16 + fg * 4 + r;
                        ((ushort*)&ab[tile][k * 5 + jq])[te] = (ushort)bfr(v[m * 4 + r]);
                    }
            }
        } else {
            // masked wave (t in [L, Lb)): a = 1/64 exactly (2 quads)
            uint4 cfill;
            cfill.x = cfill.y = cfill.z = cfill.w = 0x3C803C80u;
            ab[tile][lane * 5 + half * 2] = cfill;
            ab[tile][lane * 5 + half * 2 + 1] = cfill;
        }
        __syncthreads();
        // ---- vlad MFMA: af from LDS, bfv from xtm (L2-hot) ----
#pragma unroll
        for (int cc = 0; cc < 2; ++cc) {
            const ushort* xc2 = xtm_n + (size_t)((tbs >> 5) + cc) * 4096;
            short8 af = *(const short8*)&ab[cc][(w * 16 + fr) * 5 + fg];
#pragma unroll
            for (int cb = 0; cb < 8; ++cb) {
                short8 bfv = *(const short8*)&xc2[(cb * 16 + fr) * 32 + fg * 8];
                accB[cb] = __builtin_amdgcn_mfma_f32_16x16x32_bf16(af, bfv, accB[cb], 0, 0, 0);
            }
            accB[8] = __builtin_amdgcn_mfma_f32_16x16x32_bf16(af, onesf, accB[8], 0, 0, 0);
        }
        __syncthreads();
    }

    float* pr = part + (size_t)(n * BPN_A + blk) * (K_ * C_);
#pragma unroll
    for (int cb = 0; cb < 8; ++cb)
#pragma unroll
        for (int r = 0; r < 4; ++r)
            pr[(w * 16 + fg * 4 + r) * C_ + cb * 16 + fr] = accB[cb][r];
    if (fr == 0) {
#pragma unroll
        for (int r = 0; r < 4; ++r)
            atomicAdd(&asum[n * K_ + w * 16 + fg * 4 + r], accB[8][r]);
    }
}

// fused reduce + finalize: live partials + analytic masked term, intra-norm.
__global__ void finalize2_k(const float* __restrict__ cent,
                            const float* __restrict__ part,
                            const float* __restrict__ asum,
                            const float* __restrict__ mcs,
                            const int* __restrict__ length,
                            float* __restrict__ gsum, float* __restrict__ out) {
    int row = blockIdx.x * 4 + (threadIdx.x >> 6);  // n*64 + k
    int lane = threadIdx.x & 63;
    int n = row >> 6, k = row & 63;
    const int L = length[n];
    const int nlive = (L + 127) >> 7;      // live fused blocks
    const float* pr = part + (size_t)n * BPN_A * (K_ * C_) + k * C_;
    float y0 = 0.f, y1 = 0.f;
#pragma unroll 4
    for (int b = 0; b < nlive; ++b) {
        y0 += pr[(size_t)b * (K_ * C_) + lane];
        y1 += pr[(size_t)b * (K_ * C_) + lane + 64];
    }
    y0 += 0.015625f * mcs[n * C_ + lane];
    y1 += 0.015625f * mcs[n * C_ + lane + 64];
    float as = asum[row] + (float)(T_ - nlive * 128) * 0.015625f;
    y0 -= as * cent[k * C_ + lane];
    y1 -= as * cent[k * C_ + lane + 64];
    float ss = y0 * y0 + y1 * y1;
#pragma unroll
    for (int m = 1; m < 64; m <<= 1) ss += __shfl_xor(ss, m, 64);
    float rs = 1.0f / fmaxf(sqrtf(ss), 1e-12f);
    out[(size_t)row * C_ + lane] = y0 * rs;
    out[(size_t)row * C_ + lane + 64] = y1 * rs;
    if (lane == 0) atomicAdd(&gsum[n], ss * rs * rs);
}

__global__ void gscale2_k(float* __restrict__ out, const float* __restrict__ gsum) {
    int idx = blockIdx.x * 256 + threadIdx.x;
    int n = idx >> 13;
    out[idx] *= 1.0f / fmaxf(sqrtf(gsum[n]), 1e-12f);
}

extern "C" void kernel_launch(void* const* d_in, const int* in_sizes, int n_in,
                              void* d_out, int out_size, void* d_ws, size_t ws_size,
                              hipStream_t stream) {
    const float* x       = (const float*)d_in[0];
    const float* conv1_w = (const float*)d_in[1];
    const float* bn1_g   = (const float*)d_in[2];
    const float* bn1_b   = (const float*)d_in[3];
    const float* bn1_m   = (const float*)d_in[4];
    const float* bn1_v   = (const float*)d_in[5];
    const float* conv2_w = (const float*)d_in[6];
    const float* conv2_b = (const float*)d_in[7];
    const float* bn2_g   = (const float*)d_in[8];
    const float* bn2_b   = (const float*)d_in[9];
    const float* bn2_m   = (const float*)d_in[10];
    const float* bn2_v   = (const float*)d_in[11];
    const float* cent    = (const float*)d_in[12];
    const int*   length  = (const int*)d_in[13];
    float* out = (float*)d_out;
    float* ws  = (float*)d_ws;

    setup_k<<<4, 256, 0, stream>>>(conv1_w, bn1_g, bn1_b, bn1_m, bn1_v,
                                   conv2_w, bn2_g, bn2_v,
                                   (ushort*)(ws + NW_W2F), ws + NW_P1,
                                   ws, 4096);
    xnorm_k<<<N_ * T_ / 32, 256, 0, stream>>>(x, (ushort*)(ws + NW_XTM),
                                              length, ws + NW_MCS);
    fused_k<<<N_ * BPN_A, 256, 0, stream>>>(
        (const ushort*)(ws + NW_XTM), conv2_b, bn2_g, bn2_b, bn2_m, bn2_v,
        length, (const ushort*)(ws + NW_W2F), ws + NW_P1,
        ws + NW_PART, ws + NW_ASUM);
    finalize2_k<<<(N_ * K_) / 4, 256, 0, stream>>>(
        cent, ws + NW_PART, ws + NW_ASUM, ws + NW_MCS, length,
        ws + NW_GSUM, out);
    gscale2_k<<<(N_ * K_ * C_) / 256, 256, 0, stream>>>(out, ws + NW_GSUM);
}

// Round 16
// 71.964 us; speedup vs baseline: 1.3591x; 1.1234x over previous
//
#include <hip/hip_runtime.h>
#include <math.h>

#define N_ 16
#define T_ 8192
#define C_ 128
#define K_ 64

#define TPB_A 128      // t per fused block
#define BPN_A 64       // fused blocks per n

// ws layout in floats (67.15 MB; ws proven 268 MB by harness poison fills)
#define NW_ASUM 0              // 1024
#define NW_MCS  2048           // N*C = 2048 -> 4096  (masked colsum)
#define NW_ZBYTES (4096 * 4)   // memset region covers asum+mcs
#define NW_W2F  4096           // 4096 floats (8192 bf16)
#define NW_P1   8192           // 512 -> 8704, pad to 8960
#define NW_XTM  8960           // N*T*C bf16 = 8388608 floats -> 8397568
#define NW_PART 8397568        // N*BPN_A*K*C = 8388608 floats -> 16786176
#define NW_TOTAL 16786176

typedef __attribute__((ext_vector_type(8))) short short8;
typedef __attribute__((ext_vector_type(4))) float f32x4;

__device__ __forceinline__ uint bfr(float f) {          // fp32 -> bf16 (RNE)
    uint u = __float_as_uint(f);
    return (u + 0x7fffu + ((u >> 16) & 1u)) >> 16;
}
__device__ __forceinline__ uint pack2(float lo, float hi) {
    return bfr(lo) | (bfr(hi) << 16);
}
__device__ __forceinline__ float bfu(ushort u) {
    return __uint_as_float(((uint)u) << 16);
}

// Normalize rows, emit xn bf16 t-minor chunks [chunk=32t][128c][32t] (chunks
// up to Lb + halo), accumulate masked-region (t >= Lb) colsum into mcs.
// Blocks 0..3 additionally build the w2 fragment table + conv1/bn1 params
// (consumed only by fused_k, which launches after this kernel completes).
__global__ __launch_bounds__(256, 8) void xnorm_k(
    const float* __restrict__ x, ushort* __restrict__ xtm,
    const int* __restrict__ length, float* __restrict__ mcs,
    const float* __restrict__ conv1_w,
    const float* __restrict__ bn1_g, const float* __restrict__ bn1_b,
    const float* __restrict__ bn1_m, const float* __restrict__ bn1_v,
    const float* __restrict__ conv2_w,
    const float* __restrict__ bn2_g, const float* __restrict__ bn2_v,
    ushort* __restrict__ w2t, float* __restrict__ p1) {
    __shared__ uint xt[32][64];            // packed c-pairs, [t][c2]
    const int tid = threadIdx.x;
    const int lane = tid & 63;
    const int w = tid >> 6;
    const int n = blockIdx.x >> 8;
    const int tloc = (blockIdx.x & 255) * 32;
    const size_t row0 = (size_t)blockIdx.x * 32;
    const int L = length[n];
    const int Lb = ((L + 127) >> 7) << 7;  // live-block coverage [0, Lb)

    // ---- setup (blocks 0..3): constant tables for fused_k ----
    if (blockIdx.x < 4) {
        const int gt = blockIdx.x * 256 + tid;   // 0..1023
        for (int idx = gt; idx < 8192; idx += 1024) {
            int j = idx & 7;
            int ln = (idx >> 3) & 63;
            int mq = idx >> 9;
            int m = mq >> 2, q = mq & 3;
            int fr = ln & 15, fg = ln >> 4;
            int k = m * 16 + fr;
            float sck = bn2_g[k] * rsqrtf(bn2_v[k] + 1e-5f);
            float v = conv2_w[k * C_ + q * 32 + fg * 8 + j] * sck;
            w2t[idx] = (ushort)bfr(v);
        }
        for (int c = gt; c < C_; c += 1024) {
            float s1 = bn1_g[c] * rsqrtf(bn1_v[c] + 1e-5f);
            p1[c]       = conv1_w[c * 9 + 1] * s1;
            p1[128 + c] = conv1_w[c * 9 + 4] * s1;
            p1[256 + c] = conv1_w[c * 9 + 7] * s1;
            p1[384 + c] = bn1_b[c] - bn1_m[c] * s1;
        }
    }

#pragma unroll
    for (int i = 0; i < 8; ++i) {
        int r = w * 8 + i;
        const float* xr = x + (row0 + r) * C_;
        float2 v = *(const float2*)&xr[lane * 2];
        float ss = v.x * v.x + v.y * v.y;
#pragma unroll
        for (int m = 1; m < 64; m <<= 1) ss += __shfl_xor(ss, m, 64);
        float rn = 1.0f / fmaxf(sqrtf(ss), 1e-12f);
        xt[r][lane] = pack2(v.x * rn, v.y * rn);
    }
    __syncthreads();

    if (tloc <= Lb) {
        // consumed by fused kernel (conv halo reaches chunk Lb/32): store it
        uint4* dst = (uint4*)(xtm + (size_t)blockIdx.x * 4096);
#pragma unroll
        for (int uu = 0; uu < 2; ++uu) {
            int u = tid * 2 + uu;              // 0..511
            int c = u >> 2, j = u & 3;
            int cw = c >> 1, sh = (c & 1) * 16;
            uint o[4];
#pragma unroll
            for (int q = 0; q < 4; ++q) {
                uint lo = (xt[j * 8 + q * 2][cw] >> sh) & 0xffffu;
                uint hi = (xt[j * 8 + q * 2 + 1][cw] >> sh) & 0xffffu;
                o[q] = lo | (hi << 16);
            }
            uint4 v; v.x = o[0]; v.y = o[1]; v.z = o[2]; v.w = o[3];
            dst[u] = v;
        }
    }
    if (tloc >= Lb && w == 0) {
        // analytic masked region [Lb, T): contribution = mcs/64
        float sx = 0.f, sy = 0.f;
#pragma unroll 8
        for (int r = 0; r < 32; ++r) {
            uint u = xt[r][lane];
            sx += bfu((ushort)(u & 0xffffu));
            sy += bfu((ushort)(u >> 16));
        }
        atomicAdd(&mcs[n * C_ + lane * 2], sx);
        atomicAdd(&mcs[n * C_ + lane * 2 + 1], sy);
    }
}

// Fused: conv -> logits MFMA -> softmax -> a in LDS -> vlad MFMA (af from LDS,
// bfv from xtm/L2) -> private partials. Blocks with tb >= L return early.
__global__ __launch_bounds__(256, 3) void fused_k(
    const ushort* __restrict__ xtm,
    const float* __restrict__ conv2_b,
    const float* __restrict__ bn2_g, const float* __restrict__ bn2_b,
    const float* __restrict__ bn2_m, const float* __restrict__ bn2_v,
    const int* __restrict__ length,
    const ushort* __restrict__ w2t, const float* __restrict__ p1,
    float* __restrict__ part, float* __restrict__ asum) {

    __shared__ __align__(16) ushort w2l[8192];           // 16 KB
    __shared__ __align__(16) ushort h_s[4][16 * 136];    // 17.4 KB
    __shared__ __align__(16) uint4 ab[2][64 * 5];        // 10.2 KB

    const int tid = threadIdx.x;
    const int lane = tid & 63;
    const int w = tid >> 6;
    const int fr = lane & 15, fg = lane >> 4;
    const int tile = w >> 1, half = w & 1;
    const int n = blockIdx.x >> 6;
    const int blk = blockIdx.x & (BPN_A - 1);
    const int tb = blk * TPB_A;
    const int L = length[n];
    if (tb >= L) return;                   // analytic region (mcs)

    const ushort* xtm_n = xtm + (size_t)n * 256 * 4096;

    {
        const uint4* w2g = (const uint4*)w2t;
        uint4* w2d = (uint4*)w2l;
#pragma unroll
        for (int i = 0; i < 4; ++i) w2d[tid + i * 256] = w2g[tid + i * 256];
    }

    float wa[2], wbv[2], wcv[2], sbv[2];
#pragma unroll
    for (int p = 0; p < 2; ++p) {
        int c = lane + p * 64;
        wa[p] = p1[c]; wbv[p] = p1[128 + c];
        wcv[p] = p1[256 + c]; sbv[p] = p1[384 + c];
    }

    float sh2r[16];
#pragma unroll
    for (int m = 0; m < 4; ++m)
#pragma unroll
        for (int r = 0; r < 4; ++r) {
            int k = m * 16 + fg * 4 + r;
            float s = bn2_g[k] * rsqrtf(bn2_v[k] + 1e-5f);
            sh2r[m * 4 + r] = s * conv2_b[k] + bn2_b[k] - bn2_m[k] * s;
        }

    short8 onesf;
    {
        short f = (fr == 0) ? (short)0x3F80 : (short)0;
#pragma unroll
        for (int j = 0; j < 8; ++j) onesf[j] = f;
    }

    f32x4 accB[9];
#pragma unroll
    for (int cb = 0; cb < 9; ++cb) accB[cb] = (f32x4){0.f, 0.f, 0.f, 0.f};

    __syncthreads();

    for (int s = 0; s < TPB_A / 64; ++s) {
        const int tbs = tb + s * 64;
        const int tcs = (tbs >> 5) + tile;
        const ushort* xch = xtm_n + (size_t)tcs * 4096;
        const int t0 = tbs + tile * 32 + half * 16;

        if (t0 < L) {
            // ---- conv: lane owns c = lane, lane+64; 16 t in registers ----
            ushort* hw = h_s[w];
#pragma unroll
            for (int p = 0; p < 2; ++p) {
                const int c = lane + p * 64;
                short8 x0 = *(const short8*)&xch[c * 32 + half * 16];
                short8 x1 = *(const short8*)&xch[c * 32 + half * 16 + 8];
                float av[18];
                av[0] = 0.f; av[17] = 0.f;
                if (t0 > 0)
                    av[0] = bfu(half ? xch[c * 32 + 15] : xch[c * 32 - 4096 + 31]);
                if (t0 + 16 < T_)
                    av[17] = bfu(half ? xch[c * 32 + 4096] : xch[c * 32 + 16]);
#pragma unroll
                for (int j = 0; j < 8; ++j) {
                    av[1 + j] = bfu((ushort)x0[j]);
                    av[9 + j] = bfu((ushort)x1[j]);
                }
                float WA = wa[p], WB = wbv[p], WC = wcv[p], SB = sbv[p];
#pragma unroll
                for (int j = 0; j < 16; ++j)
                    hw[j * 136 + c] = (ushort)bfr(
                        fmaxf(0.f, av[j] * WA + av[j + 1] * WB + av[j + 2] * WC + SB));
            }
            // ---- logits MFMA (w2 from LDS; all 16 B-columns real) ----
            f32x4 accL[4];
#pragma unroll
            for (int m = 0; m < 4; ++m) accL[m] = (f32x4){0.f, 0.f, 0.f, 0.f};
            const ushort* hbp = h_s[w] + fr * 136 + fg * 8;
#pragma unroll
            for (int q = 0; q < 4; ++q) {
                short8 hf = *(const short8*)(hbp + q * 32);
                short8 w0 = *(const short8*)&w2l[((0 * 4 + q) * 64 + lane) * 8];
                short8 w1 = *(const short8*)&w2l[((1 * 4 + q) * 64 + lane) * 8];
                short8 w2f = *(const short8*)&w2l[((2 * 4 + q) * 64 + lane) * 8];
                short8 w3 = *(const short8*)&w2l[((3 * 4 + q) * 64 + lane) * 8];
                accL[0] = __builtin_amdgcn_mfma_f32_16x16x32_bf16(w0, hf, accL[0], 0, 0, 0);
                accL[1] = __builtin_amdgcn_mfma_f32_16x16x32_bf16(w1, hf, accL[1], 0, 0, 0);
                accL[2] = __builtin_amdgcn_mfma_f32_16x16x32_bf16(w2f, hf, accL[2], 0, 0, 0);
                accL[3] = __builtin_amdgcn_mfma_f32_16x16x32_bf16(w3, hf, accL[3], 0, 0, 0);
            }
            // ---- bn2 + relu + mask + softmax over k (t = t0 + fr, all lanes) ----
            {
                int t = t0 + fr;
                float v[16];
#pragma unroll
                for (int m = 0; m < 4; ++m)
#pragma unroll
                    for (int r = 0; r < 4; ++r)
                        v[m * 4 + r] = fmaxf(0.f, accL[m][r] + sh2r[m * 4 + r]);
                if (t < L) {
                    float mx = v[0];
#pragma unroll
                    for (int i = 1; i < 16; ++i) mx = fmaxf(mx, v[i]);
                    mx = fmaxf(mx, __shfl_xor(mx, 16, 64));
                    mx = fmaxf(mx, __shfl_xor(mx, 32, 64));
                    float se = 0.f;
#pragma unroll
                    for (int i = 0; i < 16; ++i) { v[i] = __expf(v[i] - mx); se += v[i]; }
                    se += __shfl_xor(se, 16, 64);
                    se += __shfl_xor(se, 32, 64);
                    float inv = 1.0f / se;
#pragma unroll
                    for (int i = 0; i < 16; ++i) v[i] *= inv;
                } else {
#pragma unroll
                    for (int i = 0; i < 16; ++i) v[i] = 0.015625f;
                }
                const int jq = half * 2 + (fr >> 3);
                const int te = fr & 7;
#pragma unroll
                for (int m = 0; m < 4; ++m)
#pragma unroll
                    for (int r = 0; r < 4; ++r) {
                        int k = m * 16 + fg * 4 + r;
                        ((ushort*)&ab[tile][k * 5 + jq])[te] = (ushort)bfr(v[m * 4 + r]);
                    }
            }
        } else {
            // masked wave (t in [L, Lb)): a = 1/64 exactly (2 quads)
            uint4 cfill;
            cfill.x = cfill.y = cfill.z = cfill.w = 0x3C803C80u;
            ab[tile][lane * 5 + half * 2] = cfill;
            ab[tile][lane * 5 + half * 2 + 1] = cfill;
        }
        __syncthreads();
        // ---- vlad MFMA: af from LDS, bfv from xtm (L2-hot) ----
#pragma unroll
        for (int cc = 0; cc < 2; ++cc) {
            const ushort* xc2 = xtm_n + (size_t)((tbs >> 5) + cc) * 4096;
            short8 af = *(const short8*)&ab[cc][(w * 16 + fr) * 5 + fg];
#pragma unroll
            for (int cb = 0; cb < 8; ++cb) {
                short8 bfv = *(const short8*)&xc2[(cb * 16 + fr) * 32 + fg * 8];
                accB[cb] = __builtin_amdgcn_mfma_f32_16x16x32_bf16(af, bfv, accB[cb], 0, 0, 0);
            }
            accB[8] = __builtin_amdgcn_mfma_f32_16x16x32_bf16(af, onesf, accB[8], 0, 0, 0);
        }
        __syncthreads();
    }

    float* pr = part + (size_t)(n * BPN_A + blk) * (K_ * C_);
#pragma unroll
    for (int cb = 0; cb < 8; ++cb)
#pragma unroll
        for (int r = 0; r < 4; ++r)
            pr[(w * 16 + fg * 4 + r) * C_ + cb * 16 + fr] = accB[cb][r];
    if (fr == 0) {
#pragma unroll
        for (int r = 0; r < 4; ++r)
            atomicAdd(&asum[n * K_ + w * 16 + fg * 4 + r], accB[8][r]);
    }
}

// fused reduce + finalize: live partials + analytic masked term, intra-norm,
// and analytic global norm: K unit-norm rows -> global scale = 1/sqrt(K) = 1/8.
__global__ void finalize2_k(const float* __restrict__ cent,
                            const float* __restrict__ part,
                            const float* __restrict__ asum,
                            const float* __restrict__ mcs,
                            const int* __restrict__ length,
                            float* __restrict__ out) {
    int row = blockIdx.x * 4 + (threadIdx.x >> 6);  // n*64 + k
    int lane = threadIdx.x & 63;
    int n = row >> 6, k = row & 63;
    const int L = length[n];
    const int nlive = (L + 127) >> 7;      // live fused blocks
    const float* pr = part + (size_t)n * BPN_A * (K_ * C_) + k * C_;
    float y0 = 0.f, y1 = 0.f;
#pragma unroll 4
    for (int b = 0; b < nlive; ++b) {
        y0 += pr[(size_t)b * (K_ * C_) + lane];
        y1 += pr[(size_t)b * (K_ * C_) + lane + 64];
    }
    y0 += 0.015625f * mcs[n * C_ + lane];
    y1 += 0.015625f * mcs[n * C_ + lane + 64];
    float as = asum[row] + (float)(T_ - nlive * 128) * 0.015625f;
    y0 -= as * cent[k * C_ + lane];
    y1 -= as * cent[k * C_ + lane + 64];
    float ss = y0 * y0 + y1 * y1;
#pragma unroll
    for (int m = 1; m < 64; m <<= 1) ss += __shfl_xor(ss, m, 64);
    float rs = 0.125f / fmaxf(sqrtf(ss), 1e-12f);   // intra-norm x global 1/8
    out[(size_t)row * C_ + lane] = y0 * rs;
    out[(size_t)row * C_ + lane + 64] = y1 * rs;
}

extern "C" void kernel_launch(void* const* d_in, const int* in_sizes, int n_in,
                              void* d_out, int out_size, void* d_ws, size_t ws_size,
                              hipStream_t stream) {
    const float* x       = (const float*)d_in[0];
    const float* conv1_w = (const float*)d_in[1];
    const float* bn1_g   = (const float*)d_in[2];
    const float* bn1_b   = (const float*)d_in[3];
    const float* bn1_m   = (const float*)d_in[4];
    const float* bn1_v   = (const float*)d_in[5];
    const float* conv2_w = (const float*)d_in[6];
    const float* conv2_b = (const float*)d_in[7];
    const float* bn2_g   = (const float*)d_in[8];
    const float* bn2_b   = (const float*)d_in[9];
    const float* bn2_m   = (const float*)d_in[10];
    const float* bn2_v   = (const float*)d_in[11];
    const float* cent    = (const float*)d_in[12];
    const int*   length  = (const int*)d_in[13];
    float* out = (float*)d_out;
    float* ws  = (float*)d_ws;

    hipMemsetAsync(ws, 0, NW_ZBYTES, stream);  // zero asum + mcs
    xnorm_k<<<N_ * T_ / 32, 256, 0, stream>>>(
        x, (ushort*)(ws + NW_XTM), length, ws + NW_MCS,
        conv1_w, bn1_g, bn1_b, bn1_m, bn1_v, conv2_w, bn2_g, bn2_v,
        (ushort*)(ws + NW_W2F), ws + NW_P1);
    fused_k<<<N_ * BPN_A, 256, 0, stream>>>(
        (const ushort*)(ws + NW_XTM), conv2_b, bn2_g, bn2_b, bn2_m, bn2_v,
        length, (const ushort*)(ws + NW_W2F), ws + NW_P1,
        ws + NW_PART, ws + NW_ASUM);
    finalize2_k<<<(N_ * K_) / 4, 256, 0, stream>>>(
        cent, ws + NW_PART, ws + NW_ASUM, ws + NW_MCS, length, out);
}